// Round 6
// baseline (653.549 us; speedup 1.0000x reference)
//
#include <hip/hip_runtime.h>
#include <hip/hip_bf16.h>

typedef unsigned long long u64;
typedef unsigned int u32;
typedef unsigned short u16;
typedef __attribute__((ext_vector_type(4))) float f32x4v;
typedef __attribute__((ext_vector_type(16))) float f32x16;
typedef __attribute__((ext_vector_type(8))) short bf16x8;  // 8 bf16 in 4 VGPRs

#define N_NODES 20000
#define N_EDGES 5000
#define FT 128
#define NT 20             // 256-col tiles per row in scan
#define NRG 313           // 64-row groups (last = 32 rows)
#define ROW_U64 80        // words per node row (edge bits)
#define COL_STRIDE 5120   // HbtT[w][e]: bit b <-> node 64w+b (plain in n)
#define XWT_S 20032       // XwT row stride (20000 padded)

#define NTLOAD(p) __builtin_nontemporal_load((const f32x4v*)(p))

static __device__ __forceinline__ u64 spread4(u64 x) {  // bit i -> bit 4i (i<16)
  x = (x | (x << 24)) & 0x000000FF000000FFull;
  x = (x | (x << 12)) & 0x000F000F000F000Full;
  x = (x | (x << 6))  & 0x0303030303030303ull;
  x = (x | (x << 3))  & 0x1111111111111111ull;
  return x;
}

static __device__ __forceinline__ u16 f2bf(float x) {   // f32 -> bf16 rn
  u32 u = __float_as_uint(x);
  u = (u + 0x7FFFu + ((u >> 16) & 1u)) >> 16;
  return (u16)u;
}

// expand 8 H-bits -> 8 bf16 {0.0, 1.0}; element j <-> bit j. Pure VALU.
static __device__ __forceinline__ bf16x8 expand8(u32 b) {
  union { u32 u[4]; bf16x8 v; } r;
  r.u[0] = (( b        & 1u) | ((( b >> 1) & 1u) << 16)) * 0x3F80u;
  r.u[1] = (((b >> 2)  & 1u) | ((( b >> 3) & 1u) << 16)) * 0x3F80u;
  r.u[2] = (((b >> 4)  & 1u) | ((( b >> 5) & 1u) << 16)) * 0x3F80u;
  r.u[3] = (((b >> 6)  & 1u) | ((( b >> 7) & 1u) << 16)) * 0x3F80u;
  return r.v;
}

// LDS swizzle for [8 chunk][32 row] bf16x8 tiles (conflict-free both sides).
static __device__ __forceinline__ int swz(int c, int r) {
  return c * 256 + (((r + c) & 31) << 3);
}

// ---------------------------------------------------------------------------
// Pass 1: NT-load ballot scan of H -> word-major row bitmask Hbt2[w][n]
// (de-interleaved, coalesced 512 B stores) + plain column bitmask HbtT,
// X->bf16 and W->bf16-transpose folded into tails.
__global__ __launch_bounds__(256) void scan_fused(
    const float* __restrict__ H, u64* __restrict__ Hbt2, u64* __restrict__ HbtT,
    const float2* __restrict__ X2, __hip_bfloat162* __restrict__ Xb2,
    const float* __restrict__ Wf, u16* __restrict__ WtB) {
  const int wid = threadIdx.x >> 6, lane = threadIdx.x & 63;

  if (blockIdx.x >= 1565) {                    // folded tails
    for (int i = (blockIdx.x - 1565) * 256 + threadIdx.x; i < 1280000;
         i += 320 * 256)
      Xb2[i] = __float22bfloat162_rn(X2[i]);
    if (blockIdx.x == 1884) {                  // WtB[f][k] = bf16(W[k][f])
      for (int i = threadIdx.x; i < FT * FT; i += 256) {
        int f = i >> 7, k = i & 127;
        WtB[i] = f2bf(Wf[k * FT + f]);
      }
    }
    return;
  }

  const int gw = blockIdx.x * 4 + wid;         // 1565*4 = 6260 = NRG*NT
  const int t = gw % NT, rg = gw / NT;
  const int r0 = rg * 64;
  const int rows = min(64, N_NODES - r0);
  const int idx4 = t * 64 + lane;
  const bool lv = idx4 < 1250;

  u64 m0 = 0, m1 = 0, m2 = 0, m3 = 0;
  for (int kb = 0; kb < rows; kb += 8) {
    f32x4v vv[8];
#pragma unroll
    for (int k = 0; k < 8; ++k) vv[k] = (f32x4v){0.f, 0.f, 0.f, 0.f};
    if (lv) {
      const float* bp = H + (size_t)(r0 + kb) * N_EDGES + idx4 * 4;
#pragma unroll
      for (int k = 0; k < 8; ++k) vv[k] = NTLOAD(bp + (size_t)k * N_EDGES);
    }
#pragma unroll
    for (int k = 0; k < 8; ++k) {
      u64 b0 = __ballot(vv[k].x != 0.f);
      u64 b1 = __ballot(vv[k].y != 0.f);
      u64 b2 = __ballot(vv[k].z != 0.f);
      u64 b3 = __ballot(vv[k].w != 0.f);
      const bool keep = (lane == kb + k);
      m0 = keep ? b0 : m0;  m1 = keep ? b1 : m1;
      m2 = keep ? b2 : m2;  m3 = keep ? b3 : m3;
    }
  }
  if (lane < rows) {                           // de-interleave -> plain words
#pragma unroll
    for (int j = 0; j < 4; ++j) {
      u64 p = spread4((m0 >> (16 * j)) & 0xFFFFull)
            | (spread4((m1 >> (16 * j)) & 0xFFFFull) << 1)
            | (spread4((m2 >> (16 * j)) & 0xFFFFull) << 2)
            | (spread4((m3 >> (16 * j)) & 0xFFFFull) << 3);
      // word-major: Hbt2[word][node], coalesced 512 B per j
      Hbt2[(size_t)(t * 4 + j) * N_NODES + (r0 + lane)] = p;
    }
  }
  u64 t0 = 0, t1 = 0, t2 = 0, t3 = 0;          // 64x64 bit transpose
  for (int l = 0; l < 64; ++l) {
    u64 c0 = __ballot((m0 >> l) & 1ull);
    u64 c1 = __ballot((m1 >> l) & 1ull);
    u64 c2 = __ballot((m2 >> l) & 1ull);
    u64 c3 = __ballot((m3 >> l) & 1ull);
    const bool keep = (lane == l);
    t0 = keep ? c0 : t0;  t1 = keep ? c1 : t1;
    t2 = keep ? c2 : t2;  t3 = keep ? c3 : t3;
  }
  u64* op = HbtT + (size_t)rg * COL_STRIDE + t * 256 + 4 * lane;
  op[0] = t0; op[1] = t1; op[2] = t2; op[3] = t3;
}

// ---------------------------------------------------------------------------
// Pass 2: XwT[f][n] = bf16( (X @ W)[n][f] ). UNCHANGED from R5 (proven).
__global__ __launch_bounds__(256) void gemm_xw(
    const u16* __restrict__ Xb, const u16* __restrict__ WtB,
    u16* __restrict__ XwT) {
  __shared__ u16 xt[4096];                     // 8 KB: [32 n][16 kc] swizzled
  const int wave = threadIdx.x >> 6, lane = threadIdx.x & 63;
  const int col = lane & 31, half = lane >> 5;
  const int n0 = blockIdx.x * 32;
  const int f0 = wave * 32;
  if (n0 >= N_NODES) {                         // block 625: zero the pad cols
    if (lane < 32)
      for (int r = 0; r < 32; ++r)
        XwT[(size_t)(f0 + r) * XWT_S + n0 + lane] = 0;
    return;
  }
  {                                            // cooperative stage, coalesced
    const int sn = threadIdx.x >> 3, sc = threadIdx.x & 7;
#pragma unroll
    for (int j = 0; j < 2; ++j) {
      bf16x8 v = *(const bf16x8*)(Xb + (size_t)(n0 + sn) * FT + (sc + 8 * j) * 8);
      *(bf16x8*)(xt + sn * 128 + (((sc + 8 * j) + sn) & 15) * 8) = v;
    }
  }
  __syncthreads();
  f32x16 acc;
#pragma unroll
  for (int i = 0; i < 16; ++i) acc[i] = 0.f;
#pragma unroll
  for (int kc = 0; kc < 16; kc += 2) {
    int c = kc + half;
    bf16x8 a = *(const bf16x8*)(WtB + (f0 + col) * FT + c * 8);
    bf16x8 b = *(const bf16x8*)(xt + col * 128 + ((c + col) & 15) * 8);
    acc = __builtin_amdgcn_mfma_f32_32x32x16_bf16(a, b, acc, 0, 0, 0);
  }
#pragma unroll
  for (int r = 0; r < 16; ++r) {
    int fr = (r & 3) + 8 * (r >> 2) + 4 * half;   // D row (verified map)
    XwT[(size_t)(f0 + fr) * XWT_S + n0 + col] = f2bf(acc[r]);
  }
}

// ---------------------------------------------------------------------------
// Pass 3: MhT[f][e] = bf16( sum_n Xw[n][f]*H[n][e] / DE[e] ).
// Grid 640 = 160 e-tiles(32) x 4 f-tiles(32); waves k-split {79,78,78,78}.
// 2-DEEP register prefetch: loads for w+2 issued while computing w, so each
// LDS write's source regs are a full iteration (~700+ cyc) old. LDS dbuf
// per wave (barrier-free); B = VALU expand8; cross-wave LDS reduce + /DE.
__global__ __launch_bounds__(256) void edge_gemm(
    const u16* __restrict__ XwT, const u64* __restrict__ HbtT,
    u16* __restrict__ MhT) {
  __shared__ u16 atile[4][2][2048];  // 32 KB: per-wave dbuf [c8][f32] swizzled
  __shared__ float sdv[4][32];       // partial DE per wave
  const int tid = threadIdx.x;
  const int wid = tid >> 6, lane = tid & 63;
  const int col = lane & 31, half = lane >> 5;

  const int et = blockIdx.x % 160, ft = blockIdx.x / 160;
  const int e0 = et * 32, f0 = ft * 32;
  const int ws_ = wid * 78 + (wid > 0 ? 1 : 0);       // 0,79,157,235
  const int we_ = ws_ + (wid == 0 ? 79 : 78);         // 79,157,235,313

  const int srow = lane >> 3, schunk = lane & 7;
  const u16* sgbase = XwT + (size_t)(f0 + srow) * XWT_S + schunk * 8;
  u16* buf0 = &atile[wid][0][0];
  u16* buf1 = &atile[wid][1][0];

  f32x16 acc;
#pragma unroll
  for (int i = 0; i < 16; ++i) acc[i] = 0.f;
  float dv = 0.f;

  bf16x8 rB[4], rC[4];
  {                                            // prologue: w and w+1
    const int w1 = (ws_ + 1 < we_) ? ws_ + 1 : ws_;
    bf16x8 rA[4];
#pragma unroll
    for (int j = 0; j < 4; ++j)
      rA[j] = *(const bf16x8*)(sgbase + (size_t)(8 * j) * XWT_S + ws_ * 64);
#pragma unroll
    for (int j = 0; j < 4; ++j)
      rB[j] = *(const bf16x8*)(sgbase + (size_t)(8 * j) * XWT_S + w1 * 64);
#pragma unroll
    for (int j = 0; j < 4; ++j)
      *(bf16x8*)(buf0 + swz(schunk, srow + 8 * j)) = rA[j];
  }
  u64 h0 = HbtT[(size_t)ws_ * COL_STRIDE + e0 + col];
  u64 h1 = HbtT[(size_t)((ws_ + 1 < we_) ? ws_ + 1 : ws_) * COL_STRIDE + e0 + col];

  int p = 0;
  for (int w = ws_; w < we_; ++w) {
    const int w2 = (w + 2 < we_) ? w + 2 : we_ - 1;
#pragma unroll
    for (int j = 0; j < 4; ++j)                // issue loads for w+2
      rC[j] = *(const bf16x8*)(sgbase + (size_t)(8 * j) * XWT_S + w2 * 64);
    u64 h2 = HbtT[(size_t)w2 * COL_STRIDE + e0 + col];

    const u16* ab = p ? buf1 : buf0;           // compute current (w)
#pragma unroll
    for (int q = 0; q < 4; ++q) {
      bf16x8 a = *(const bf16x8*)(ab + swz(2 * q + half, col));
      bf16x8 b = expand8((u32)(h0 >> (q * 16 + half * 8)) & 0xFFu);
      acc = __builtin_amdgcn_mfma_f32_32x32x16_bf16(a, b, acc, 0, 0, 0);
    }
    dv += (float)__popcll(h0);

    u16* nb = p ? buf0 : buf1;                 // write w+1 (regs 1 iter old)
#pragma unroll
    for (int j = 0; j < 4; ++j)
      *(bf16x8*)(nb + swz(schunk, srow + 8 * j)) = rB[j];
#pragma unroll
    for (int j = 0; j < 4; ++j) rB[j] = rC[j];
    h0 = h1; h1 = h2; p ^= 1;
  }

  // dump acc into own atile region (reused as 1024-f32 scratch per wave)
  float* sacc = (float*)&atile[wid][0][0];
#pragma unroll
  for (int r = 0; r < 16; ++r) {
    int fr = (r & 3) + 8 * (r >> 2) + 4 * half;
    sacc[fr * 32 + col] = acc[r];
  }
  if (half == 0) sdv[wid][col] = dv;
  __syncthreads();

  {                                            // cross-wave reduce + /DE + bf16
    const int frl = tid >> 3, eq = tid & 7;    // 32 f-rows x 8 e-quads
    const float* s0 = (const float*)&atile[0][0][0];
    union { u16 h[4]; u64 q; } o;
#pragma unroll
    for (int j = 0; j < 4; ++j) {
      int e = eq * 4 + j;
      int idx = frl * 32 + e;
      float s = s0[idx] + s0[2048 + idx] + s0[4096 + idx] + s0[6144 + idx];
      float d = sdv[0][e] + sdv[1][e] + sdv[2][e] + sdv[3][e];
      o.h[j] = f2bf(s / (d + 1e-12f));
    }
    *(u64*)(MhT + (size_t)(f0 + frl) * COL_STRIDE + e0 + eq * 4) = o.q;
  }
}

// ---------------------------------------------------------------------------
// Pass 4: out[n][f] = relu( (H @ M)[n][f] / DV[n] + bias[f] ).
// Grid 625 x 4 f-waves, wave-independent 32n x 32f, zero barriers.
// Hbt2 word-major -> coalesced 256 B word loads (was 32-line scatter).
// 2-DEEP register prefetch on both the MhT slices and the Hbt2 words.
__global__ __launch_bounds__(256) void node_gemm(
    const u64* __restrict__ Hbt2, const u16* __restrict__ MhT,
    const float* __restrict__ bias, float* __restrict__ out) {
  __shared__ u16 btile[4][2][2048];  // 32 KB: per-wave dbuf [c8][f32] swizzled
  const int tid = threadIdx.x;
  const int wid = tid >> 6, lane = tid & 63;
  const int col = lane & 31, half = lane >> 5;
  const int n0 = blockIdx.x * 32;
  const int f0 = wid * 32;

  const int srow = lane >> 3, schunk = lane & 7;
  const u16* sgbase = MhT + (size_t)(f0 + srow) * COL_STRIDE + schunk * 8;
  u16* buf0 = &btile[wid][0][0];
  u16* buf1 = &btile[wid][1][0];

  f32x16 acc;
#pragma unroll
  for (int i = 0; i < 16; ++i) acc[i] = 0.f;
  float dv = 0.f;

  bf16x8 rB[4], rC[4];
  {                                            // prologue: w=0 and w=1
    bf16x8 rA[4];
#pragma unroll
    for (int j = 0; j < 4; ++j)
      rA[j] = *(const bf16x8*)(sgbase + (size_t)(8 * j) * COL_STRIDE);
#pragma unroll
    for (int j = 0; j < 4; ++j)
      rB[j] = *(const bf16x8*)(sgbase + (size_t)(8 * j) * COL_STRIDE + 64);
#pragma unroll
    for (int j = 0; j < 4; ++j)
      *(bf16x8*)(buf0 + swz(schunk, srow + 8 * j)) = rA[j];
  }
  u64 h0 = Hbt2[(size_t)0 * N_NODES + n0 + col];
  u64 h1 = Hbt2[(size_t)1 * N_NODES + n0 + col];

  int p = 0;
  for (int w = 0; w < ROW_U64; ++w) {
    const int w2 = (w + 2 < ROW_U64) ? w + 2 : ROW_U64 - 1;
#pragma unroll
    for (int j = 0; j < 4; ++j)                // issue loads for w+2
      rC[j] = *(const bf16x8*)(sgbase + (size_t)(8 * j) * COL_STRIDE + w2 * 64);
    u64 h2 = Hbt2[(size_t)w2 * N_NODES + n0 + col];

    const u16* bb = p ? buf1 : buf0;           // compute current (w)
#pragma unroll
    for (int q = 0; q < 4; ++q) {
      bf16x8 a = expand8((u32)(h0 >> (q * 16 + half * 8)) & 0xFFu);
      bf16x8 b = *(const bf16x8*)(bb + swz(2 * q + half, col));
      acc = __builtin_amdgcn_mfma_f32_32x32x16_bf16(a, b, acc, 0, 0, 0);
    }
    dv += (float)__popcll(h0);

    u16* nb = p ? buf0 : buf1;                 // write w+1 (regs 1 iter old)
#pragma unroll
    for (int j = 0; j < 4; ++j)
      *(bf16x8*)(nb + swz(schunk, srow + 8 * j)) = rB[j];
#pragma unroll
    for (int j = 0; j < 4; ++j) rB[j] = rC[j];
    h0 = h1; h1 = h2; p ^= 1;
  }

  float inv = 1.f / (dv + 1e-12f);             // lanes 0..31: col <-> node
  float bb = bias[f0 + col];
#pragma unroll
  for (int r = 0; r < 16; ++r) {
    int rr = (r & 3) + 8 * (r >> 2) + 4 * half;    // D row = node-local
    float iv = __shfl(inv, rr);
    out[(size_t)(n0 + rr) * FT + f0 + col] = fmaxf(fmaf(acc[r], iv, bb), 0.f);
  }
}

extern "C" void kernel_launch(void* const* d_in, const int* in_sizes, int n_in,
                              void* d_out, int out_size, void* d_ws, size_t ws_size,
                              hipStream_t stream) {
  const float* X    = (const float*)d_in[0];   // [20000, 128]
  const float* H    = (const float*)d_in[1];   // [20000, 5000] dense 0/1
  const float* W    = (const float*)d_in[2];   // [128, 128]
  const float* bias = (const float*)d_in[3];   // [128]
  float* out = (float*)d_out;                  // [20000, 128] fp32

  // Workspace (int units), 35.9 MB (proven footprint). MhT aliases Xb2
  // (Xb2 dead after gemm_xw; MhT first written by edge_gemm).
  int* ws = (int*)d_ws;
  u64* Hbt2            = (u64*)ws;                          // [80][20000] u64
  u64* HbtT            = (u64*)(ws + 3200000);              // 313*5120 u64
  __hip_bfloat162* Xb2 = (__hip_bfloat162*)(ws + 6405120);  // 1,280,000 ints
  u16* MhT             = (u16*)(ws + 6405120);              // 128*5120 bf16 (alias)
  u16* WtB             = (u16*)(ws + 7685120);              // 16,384 bf16
  u16* XwT             = (u16*)(ws + 7693312);              // 128*20032 bf16
  // end: 8,975,360 ints = 35.9 MB

  scan_fused<<<1885, 256, 0, stream>>>(H, Hbt2, HbtT, (const float2*)X, Xb2,
                                       W, WtB);
  gemm_xw   <<<626, 256, 0, stream>>>((const u16*)Xb2, WtB, XwT);
  edge_gemm <<<640, 256, 0, stream>>>(XwT, HbtT, MhT);
  node_gemm <<<625, 256, 0, stream>>>(Hbt2, MhT, bias, out);
}